// Round 2
// baseline (50341.580 us; speedup 1.0000x reference)
//
#include <hip/hip_runtime.h>
#include <math.h>

// GRU encoder, B=64 T=2048 E=256 H=512 V=32000.
// prep   : Wcat (B-fragment-order bf16 of [Wr;Wz;Wxh]) + fused biases + lengths
// gemm_x : per T-chunk, gather emb rows (fp32->bf16) into LDS and compute
//          x-projections xbuf[b,t,j] = bf16(Xemb . Wcat_j + bias_j) via MFMA
// scan   : persistent recurrence, 8 clusters x 32 single-wave WGs; recurrent
//          weights live in registers as MFMA A-frags; atomic cluster barriers.
//          Chunked: h state persists across launches via h_final (fp32).
// Output head tanh(h V^T + V_b) fused into last scan launch.
// Workspace footprint adapts to ws_size via chunk count NC (deterministic).

typedef unsigned short u16;
typedef __attribute__((ext_vector_type(8))) short s16x8;
typedef __attribute__((ext_vector_type(4))) unsigned short u16x4;
typedef __attribute__((ext_vector_type(4))) float f32x4;

#define MFMA16(a,b,c) __builtin_amdgcn_mfma_f32_16x16x32_bf16((a),(b),(c),0,0,0)

__device__ __forceinline__ short f2bf(float f) {
  union { float f; unsigned u; } x; x.f = f;
  unsigned r = x.u + 0x7FFFu + ((x.u >> 16) & 1u);  // RNE
  return (short)(r >> 16);
}
__device__ __forceinline__ float bf2f(unsigned short u) {
  union { unsigned u; float f; } x; x.u = ((unsigned)u) << 16;
  return x.f;
}
__device__ __forceinline__ s16x8 cvt8(const float* p) {
  float4 a = *(const float4*)p;
  float4 b = *(const float4*)(p + 4);
  s16x8 r;
  r[0]=f2bf(a.x); r[1]=f2bf(a.y); r[2]=f2bf(a.z); r[3]=f2bf(a.w);
  r[4]=f2bf(b.x); r[5]=f2bf(b.y); r[6]=f2bf(b.z); r[7]=f2bf(b.w);
  return r;
}
__device__ __forceinline__ float sigm(float x){ return 1.0f/(1.0f + __expf(-x)); }
__device__ __forceinline__ float ftanh(float x){ float e = __expf(2.0f*x); return 1.0f - 2.0f/(e + 1.0f); }

// ---------------- prep: Wcat (frag-order bf16), fused biases, lengths ----------------
__global__ void prep_kernel(const int* __restrict__ X,
                            const float* __restrict__ Wr_w, const float* __restrict__ Wz_w,
                            const float* __restrict__ Wxh_w,
                            const float* __restrict__ Wr_b, const float* __restrict__ Ur_b,
                            const float* __restrict__ Wz_b, const float* __restrict__ Uz_b,
                            const float* __restrict__ Wxh_b, const float* __restrict__ Whh_b,
                            u16* __restrict__ Wcat, float* __restrict__ bias_cat,
                            int* __restrict__ lengths) {
  const int bid = blockIdx.x, tid = threadIdx.x;
  if (bid < 64) {
    __shared__ int sred[256];
    int s = 0;
    for (int i = tid; i < 2048; i += 256) s += (X[bid*2048 + i] != 0) ? 1 : 0;
    sred[tid] = s; __syncthreads();
    for (int st = 128; st > 0; st >>= 1) { if (tid < st) sred[tid] += sred[tid + st]; __syncthreads(); }
    if (tid == 0) lengths[bid] = sred[0];
  } else if (bid < 1600) {
    // Wcat layout [s(96)][lane(64)][e(8)] grouped by ks inside: value = W[j][k],
    // j = s*16 + (lane&15), k = ks*32 + (lane>>4)*8 + e  (B-fragment order)
    const int eid = (bid - 64)*256 + tid;      // < 393216
    const int e = eid & 7, lane = (eid >> 3) & 63, ks = (eid >> 9) & 7, s = eid >> 12;
    const int j = s*16 + (lane & 15);
    const int k = ks*32 + ((lane >> 4) << 3) + e;
    float v;
    if (j < 512)       v = Wr_w[j*256 + k];
    else if (j < 1024) v = Wz_w[(j-512)*256 + k];
    else               v = Wxh_w[(j-1024)*256 + k];
    Wcat[eid] = (u16)f2bf(v);
  } else {
    const int j = (bid - 1600)*256 + tid;
    if (j < 1536) {
      float v;
      if (j < 512)       v = Wr_b[j] + Ur_b[j];          // fold U-bias into x-projection
      else if (j < 1024) v = Wz_b[j-512] + Uz_b[j-512];
      else               v = Wxh_b[j-1024] + Whh_b[j-1024];
      bias_cat[j] = v;
    }
  }
}

// ---------------- gemm_x: xbuf[row][j] = bf16( emb[X] . Wcat_j + bias[j] ) ----------------
// One chunk of chunkT timesteps. Local row = tl*64 + b. Block = (128-row tile, j-half).
// Embedding gather fused into the LDS staging (no Xemb buffer).
__launch_bounds__(256, 2)
__global__ void gemm_x_kernel(const int* __restrict__ X, const float* __restrict__ emb,
                              const u16* __restrict__ Wcat, const float* __restrict__ bias,
                              u16* __restrict__ xbuf, int t0) {
  __shared__ __align__(16) u16 Alds[32768];  // 64 KiB, fragment-ordered A tile
  const int tile = blockIdx.x >> 1, jh = blockIdx.x & 1;
  const int tid = threadIdx.x;
  const int rbase = tile * 128;              // local chunk row base
#pragma unroll
  for (int c = 0; c < 16; ++c) {
    const int id = c * 256 + tid;            // 4096 16B-chunks: 128 rows x 32
    const int row = id >> 5, k8 = id & 31;
    const int lr = rbase + row;
    const int b = lr & 63, t = t0 + (lr >> 6);
    int v = X[b*2048 + t];
    v = ((unsigned)v < 32000u) ? v : 0;      // defensive clamp
    s16x8 val = cvt8(emb + (long)v*256 + (k8 << 3));
    const int lane = (row & 15) | ((k8 & 3) << 4);
    const int slot = ((row >> 4)*8 + (k8 >> 2))*64 + lane;
    *(s16x8*)(&Alds[slot << 3]) = val;
  }
  __syncthreads();
  const int w = tid >> 6, l = tid & 63;
  s16x8 af[2][8];                            // rows w*32+m*16+(l&15), all 8 k-chunks
#pragma unroll
  for (int m = 0; m < 2; ++m)
#pragma unroll
    for (int ks = 0; ks < 8; ++ks)
      af[m][ks] = *(const s16x8*)(&Alds[((((w*2+m)*8 + ks)*64) + l) << 3]);
  for (int s = jh*48; s < jh*48 + 48; ++s) { // 16-wide j-subtiles
    s16x8 bfr[8];
    const long wco = (long)s * 4096;
#pragma unroll
    for (int ks = 0; ks < 8; ++ks)
      bfr[ks] = *(const s16x8*)(Wcat + wco + ((ks*64 + l) << 3));
    f32x4 a0 = {0.f,0.f,0.f,0.f}, a1 = {0.f,0.f,0.f,0.f};
#pragma unroll
    for (int ks = 0; ks < 8; ++ks) {
      a0 = MFMA16(af[0][ks], bfr[ks], a0);
      a1 = MFMA16(af[1][ks], bfr[ks], a1);
    }
    const int j = s*16 + (l & 15);
    const float badd = bias[j];
    const int i0 = rbase + w*32 + ((l >> 4) << 2);
#pragma unroll
    for (int e = 0; e < 4; ++e) {
      xbuf[(long)(i0 + e)*1536 + j]      = (u16)f2bf(a0[e] + badd);
      xbuf[(long)(i0 + 16 + e)*1536 + j] = (u16)f2bf(a1[e] + badd);
    }
  }
}

// ---------------- scan: persistent recurrence over one T-chunk ----------------
// 256 blocks x 64 threads. cluster c = blockIdx&7 (all members on XCD c) owns
// batch rows [8c,8c+8); member m = blockIdx>>3 owns H-dims [16m,16m+16).
__launch_bounds__(64, 1)
__global__ void scan_kernel(const float* __restrict__ Ur_w, const float* __restrict__ Uz_w,
                            const float* __restrict__ Whh_w, const u16* __restrict__ xbuf,
                            const int* __restrict__ lengths, const float* __restrict__ V_w,
                            const float* __restrict__ V_b, u16* __restrict__ h_bc,
                            u16* __restrict__ rh_bc, float* __restrict__ h_final,
                            unsigned* __restrict__ cnt, float* __restrict__ out,
                            int t0, int nsteps, int last) {
  const int wg = blockIdx.x;
  const int c = wg & 7, mem = wg >> 3;
  const int l = threadIdx.x;
  const int n = l & 15, kg = l >> 4;
  const int jb = mem * 16;
  const bool act = (n < 8);
  const int nc = act ? n : 7;
  const int rowb = c * 8;

  // recurrent weights -> registers (A-frags: lane holds row jb+n, k-chunk kg*8)
  s16x8 wr[16], wz[16], wh[16];
  {
    const int wrow = jb + n;
    const float* pr = Ur_w  + wrow*512;
    const float* pz = Uz_w  + wrow*512;
    const float* ph = Whh_w + wrow*512;
#pragma unroll
    for (int ks = 0; ks < 16; ++ks) {
      const int o = ks*32 + (kg << 3);
      wr[ks] = cvt8(pr + o); wz[ks] = cvt8(pz + o); wh[ks] = cvt8(ph + o);
    }
  }
  const int mylen = lengths[rowb + nc];
  const u16* xp = xbuf + (rowb + nc)*1536 + jb + (kg << 2);  // + tl*98304 per step
  u16x4 pxr = *(const u16x4*)(xp);
  u16x4 pxz = *(const u16x4*)(xp + 512);
  u16x4 pxh = *(const u16x4*)(xp + 1024);

  const u16* hbp = h_bc  + c*8192 + n*512 + (kg << 3);
  const u16* rbp = rh_bc + c*8192 + n*512 + (kg << 3);
  u16* hst_p = h_bc  + (c*16 + n)*512 + jb + (kg << 2);
  u16* rst_p = rh_bc + (c*16 + n)*512 + jb + (kg << 2);
  unsigned* bar = cnt + c*16;                // one cacheline per cluster

  float h[4];
  if (t0 == 0) {
    h[0]=0.f; h[1]=0.f; h[2]=0.f; h[3]=0.f;
  } else {
    float4 hv = *(const float4*)(h_final + (rowb + nc)*512 + jb + (kg << 2));
    h[0]=hv.x; h[1]=hv.y; h[2]=hv.z; h[3]=hv.w;
  }
  unsigned gen = 2u * (unsigned)t0;          // barrier generation continues across launches

  for (int tl = 0; tl < nsteps; ++tl) {
    // ---- phase A: [Ur;Uz] @ h ----
    s16x8 hf[16];
#pragma unroll
    for (int ks = 0; ks < 16; ++ks) hf[ks] = *(const s16x8*)(hbp + ks*32);
    const int tn = (tl < nsteps-1) ? (tl + 1) : tl;
    const u16* xq = xp + tn*98304;           // prefetch next step's x
    u16x4 nxr = *(const u16x4*)(xq);
    u16x4 nxz = *(const u16x4*)(xq + 512);
    u16x4 nxh = *(const u16x4*)(xq + 1024);
    f32x4 ar = {0.f,0.f,0.f,0.f}, az = {0.f,0.f,0.f,0.f};
#pragma unroll
    for (int ks = 0; ks < 16; ++ks) {
      ar = MFMA16(wr[ks], hf[ks], ar);
      az = MFMA16(wz[ks], hf[ks], az);
    }
    float zz[4]; u16x4 rst;
#pragma unroll
    for (int e = 0; e < 4; ++e) {
      float rr = sigm(ar[e] + bf2f(pxr[e]));
      zz[e]    = sigm(az[e] + bf2f(pxz[e]));
      rst[e]   = (u16)f2bf(rr * h[e]);
    }
    if (act) *(u16x4*)rst_p = rst;
    __threadfence();
    ++gen;
    if (l == 0) __hip_atomic_fetch_add(bar, 1u, __ATOMIC_RELEASE, __HIP_MEMORY_SCOPE_AGENT);
    while (__hip_atomic_load(bar, __ATOMIC_ACQUIRE, __HIP_MEMORY_SCOPE_AGENT) < 32u*gen) {}
    // ---- phase B: Whh @ (r*h), gate update ----
    s16x8 rf[16];
#pragma unroll
    for (int ks = 0; ks < 16; ++ks) rf[ks] = *(const s16x8*)(rbp + ks*32);
    f32x4 au = {0.f,0.f,0.f,0.f};
#pragma unroll
    for (int ks = 0; ks < 16; ++ks) au = MFMA16(wh[ks], rf[ks], au);
    u16x4 hstv;
#pragma unroll
    for (int e = 0; e < 4; ++e) {
      float upd = ftanh(au[e] + bf2f(pxh[e]));
      float hn  = zz[e]*h[e] + (1.f - zz[e])*upd;
      h[e] = ((t0 + tl) < mylen) ? hn : h[e];
      hstv[e] = (u16)f2bf(h[e]);
    }
    if (act) *(u16x4*)hst_p = hstv;
    __threadfence();
    ++gen;
    if (l == 0) __hip_atomic_fetch_add(bar, 1u, __ATOMIC_RELEASE, __HIP_MEMORY_SCOPE_AGENT);
    while (__hip_atomic_load(bar, __ATOMIC_ACQUIRE, __HIP_MEMORY_SCOPE_AGENT) < 32u*gen) {}
    pxr = nxr; pxz = nxz; pxh = nxh;
  }
  // persist hidden state (fp32) for next chunk / output head
  if (act) {
    float4 hv; hv.x = h[0]; hv.y = h[1]; hv.z = h[2]; hv.w = h[3];
    *(float4*)(h_final + (rowb + n)*512 + jb + (kg << 2)) = hv;
  }
  if (!last) return;                         // kernel end = device-wide visibility
  __threadfence();
  ++gen;
  if (l == 0) __hip_atomic_fetch_add(bar, 1u, __ATOMIC_RELEASE, __HIP_MEMORY_SCOPE_AGENT);
  while (__hip_atomic_load(bar, __ATOMIC_ACQUIRE, __HIP_MEMORY_SCOPE_AGENT) < 32u*gen) {}
  // out = tanh(hT @ V^T + V_b): this WG covers its 16 dims x its 8 rows
  {
    const int nn = l & 7, jo = l >> 3;       // jo in [0,8)
    const int j1 = jb + jo, j2 = jb + 8 + jo;
    const float* hrow = h_final + (rowb + nn)*512;
    const float* v1 = V_w + j1*512;
    const float* v2 = V_w + j2*512;
    float a1 = 0.f, a2 = 0.f;
    for (int k = 0; k < 512; k += 4) {
      float4 hv = *(const float4*)(hrow + k);
      float4 w1 = *(const float4*)(v1 + k);
      float4 w2 = *(const float4*)(v2 + k);
      a1 += hv.x*w1.x + hv.y*w1.y + hv.z*w1.z + hv.w*w1.w;
      a2 += hv.x*w2.x + hv.y*w2.y + hv.z*w2.z + hv.w*w2.w;
    }
    out[(rowb + nn)*512 + j1] = ftanh(a1 + V_b[j1]);
    out[(rowb + nn)*512 + j2] = ftanh(a2 + V_b[j2]);
  }
}

extern "C" void kernel_launch(void* const* d_in, const int* in_sizes, int n_in,
                              void* d_out, int out_size, void* d_ws, size_t ws_size,
                              hipStream_t stream) {
  const int*   X     = (const int*)d_in[0];
  const float* emb   = (const float*)d_in[1];
  const float* Wr_w  = (const float*)d_in[2];
  const float* Wr_b  = (const float*)d_in[3];
  const float* Ur_w  = (const float*)d_in[4];
  const float* Ur_b  = (const float*)d_in[5];
  const float* Wz_w  = (const float*)d_in[6];
  const float* Wz_b  = (const float*)d_in[7];
  const float* Uz_w  = (const float*)d_in[8];
  const float* Uz_b  = (const float*)d_in[9];
  const float* Wxh_w = (const float*)d_in[10];
  const float* Wxh_b = (const float*)d_in[11];
  const float* Whh_w = (const float*)d_in[12];
  const float* Whh_b = (const float*)d_in[13];
  const float* V_w   = (const float*)d_in[14];
  const float* V_b   = (const float*)d_in[15];
  (void)in_sizes; (void)n_in; (void)out_size;

  char* ws = (char*)d_ws;
  u16*      Wcat = (u16*)ws;                      //     786,432 B
  float*    bias = (float*)(ws + 786432L);        //       6,144 B
  int*      len  = (int*)(ws + 792576L);          //         256 B
  float*    hfin = (float*)(ws + 792832L);        //     131,072 B
  u16*      hbc  = (u16*)(ws + 923904L);          //     131,072 B
  u16*      rbc  = (u16*)(ws + 1054976L);         //     131,072 B
  unsigned* cnt  = (unsigned*)(ws + 1186048L);    //         512 B
  u16*      xbuf = (u16*)(ws + 1186560L);         // 402,653,184/NC B

  // pick the largest x-projection chunk that fits the workspace (deterministic)
  const long avail = (long)ws_size - 1186560L;
  int NC = 1;
  while (NC < 32 && (402653184L / NC) > avail) NC <<= 1;
  const int chunkT = 2048 / NC;

  // reset h0 (zeros), rh pad rows, and barrier counters every launch (replay-safe)
  hipMemsetAsync(hbc, 0, 131072 + 131072 + 512, stream);
  prep_kernel<<<1606, 256, 0, stream>>>(X, Wr_w, Wz_w, Wxh_w, Wr_b, Ur_b, Wz_b, Uz_b,
                                        Wxh_b, Whh_b, Wcat, bias, len);
  for (int c = 0; c < NC; ++c) {
    gemm_x_kernel<<<chunkT, 256, 0, stream>>>(X, emb, Wcat, bias, xbuf, c*chunkT);
    scan_kernel<<<256, 64, 0, stream>>>(Ur_w, Uz_w, Whh_w, xbuf, len, V_w, V_b,
                                        hbc, rbc, hfin, cnt, (float*)d_out,
                                        c*chunkT, chunkT, (c == NC-1) ? 1 : 0);
  }
}

// Round 3
// 10770.553 us; speedup vs baseline: 4.6740x; 4.6740x over previous
//
#include <hip/hip_runtime.h>
#include <math.h>

// GRU encoder, B=64 T=2048 E=256 H=512 V=32000.
// prep   : Wcat (B-fragment-order bf16 of [Wr;Wz;Wxh]) + fused biases + lengths
// gemm_x : per T-chunk, gather emb rows (fp32->bf16) into LDS and compute
//          x-projections xbuf[b,t,j] = bf16(Xemb . Wcat_j + bias_j) via MFMA
// scan   : persistent recurrence, 8 clusters x 32 single-wave WGs; recurrent
//          weights in LDS as MFMA A-frags; cross-WG sync via explicit sc0/sc1
//          coherence-point ops (no buffer_wbl2/buffer_inv L2 flushes).
// Output head tanh(h V^T + V_b) fused into last scan launch.

typedef unsigned short u16;
typedef __attribute__((ext_vector_type(8))) short s16x8;
typedef __attribute__((ext_vector_type(4))) unsigned short u16x4;
typedef __attribute__((ext_vector_type(4))) float f32x4;
typedef __attribute__((ext_vector_type(2))) unsigned u32x2;

#define MFMA16(a,b,c) __builtin_amdgcn_mfma_f32_16x16x32_bf16((a),(b),(c),0,0,0)

__device__ __forceinline__ short f2bf(float f) {
  union { float f; unsigned u; } x; x.f = f;
  unsigned r = x.u + 0x7FFFu + ((x.u >> 16) & 1u);  // RNE
  return (short)(r >> 16);
}
__device__ __forceinline__ float bf2f(unsigned short u) {
  union { unsigned u; float f; } x; x.u = ((unsigned)u) << 16;
  return x.f;
}
__device__ __forceinline__ s16x8 cvt8(const float* p) {
  float4 a = *(const float4*)p;
  float4 b = *(const float4*)(p + 4);
  s16x8 r;
  r[0]=f2bf(a.x); r[1]=f2bf(a.y); r[2]=f2bf(a.z); r[3]=f2bf(a.w);
  r[4]=f2bf(b.x); r[5]=f2bf(b.y); r[6]=f2bf(b.z); r[7]=f2bf(b.w);
  return r;
}
__device__ __forceinline__ float sigm(float x){ return 1.0f/(1.0f + __expf(-x)); }
__device__ __forceinline__ float ftanh(float x){ float e = __expf(2.0f*x); return 1.0f - 2.0f/(e + 1.0f); }

// 16 coherence-point 16B loads (step 64 B) + waitcnt, single asm block so no
// instruction can slip between the loads and their wait (rule #18).
#define LOAD16_SC64(d, base)                                                   \
  asm volatile(                                                                \
    "global_load_dwordx4 %0, %16, off sc0 sc1\n\t"                             \
    "global_load_dwordx4 %1, %16, off offset:64 sc0 sc1\n\t"                   \
    "global_load_dwordx4 %2, %16, off offset:128 sc0 sc1\n\t"                  \
    "global_load_dwordx4 %3, %16, off offset:192 sc0 sc1\n\t"                  \
    "global_load_dwordx4 %4, %16, off offset:256 sc0 sc1\n\t"                  \
    "global_load_dwordx4 %5, %16, off offset:320 sc0 sc1\n\t"                  \
    "global_load_dwordx4 %6, %16, off offset:384 sc0 sc1\n\t"                  \
    "global_load_dwordx4 %7, %16, off offset:448 sc0 sc1\n\t"                  \
    "global_load_dwordx4 %8, %16, off offset:512 sc0 sc1\n\t"                  \
    "global_load_dwordx4 %9, %16, off offset:576 sc0 sc1\n\t"                  \
    "global_load_dwordx4 %10, %16, off offset:640 sc0 sc1\n\t"                 \
    "global_load_dwordx4 %11, %16, off offset:704 sc0 sc1\n\t"                 \
    "global_load_dwordx4 %12, %16, off offset:768 sc0 sc1\n\t"                 \
    "global_load_dwordx4 %13, %16, off offset:832 sc0 sc1\n\t"                 \
    "global_load_dwordx4 %14, %16, off offset:896 sc0 sc1\n\t"                 \
    "global_load_dwordx4 %15, %16, off offset:960 sc0 sc1\n\t"                 \
    "s_waitcnt vmcnt(0)"                                                       \
    : "=v"(d[0]),"=v"(d[1]),"=v"(d[2]),"=v"(d[3]),"=v"(d[4]),"=v"(d[5]),       \
      "=v"(d[6]),"=v"(d[7]),"=v"(d[8]),"=v"(d[9]),"=v"(d[10]),"=v"(d[11]),     \
      "=v"(d[12]),"=v"(d[13]),"=v"(d[14]),"=v"(d[15])                          \
    : "v"(base) : "memory")

// same but 16B-contiguous (step 16 B) for the output-head h staging
#define LOAD16_SC16(d, base)                                                   \
  asm volatile(                                                                \
    "global_load_dwordx4 %0, %16, off sc0 sc1\n\t"                             \
    "global_load_dwordx4 %1, %16, off offset:16 sc0 sc1\n\t"                   \
    "global_load_dwordx4 %2, %16, off offset:32 sc0 sc1\n\t"                   \
    "global_load_dwordx4 %3, %16, off offset:48 sc0 sc1\n\t"                   \
    "global_load_dwordx4 %4, %16, off offset:64 sc0 sc1\n\t"                   \
    "global_load_dwordx4 %5, %16, off offset:80 sc0 sc1\n\t"                   \
    "global_load_dwordx4 %6, %16, off offset:96 sc0 sc1\n\t"                   \
    "global_load_dwordx4 %7, %16, off offset:112 sc0 sc1\n\t"                  \
    "global_load_dwordx4 %8, %16, off offset:128 sc0 sc1\n\t"                  \
    "global_load_dwordx4 %9, %16, off offset:144 sc0 sc1\n\t"                  \
    "global_load_dwordx4 %10, %16, off offset:160 sc0 sc1\n\t"                 \
    "global_load_dwordx4 %11, %16, off offset:176 sc0 sc1\n\t"                 \
    "global_load_dwordx4 %12, %16, off offset:192 sc0 sc1\n\t"                 \
    "global_load_dwordx4 %13, %16, off offset:208 sc0 sc1\n\t"                 \
    "global_load_dwordx4 %14, %16, off offset:224 sc0 sc1\n\t"                 \
    "global_load_dwordx4 %15, %16, off offset:240 sc0 sc1\n\t"                 \
    "s_waitcnt vmcnt(0)"                                                       \
    : "=v"(d[0]),"=v"(d[1]),"=v"(d[2]),"=v"(d[3]),"=v"(d[4]),"=v"(d[5]),       \
      "=v"(d[6]),"=v"(d[7]),"=v"(d[8]),"=v"(d[9]),"=v"(d[10]),"=v"(d[11]),     \
      "=v"(d[12]),"=v"(d[13]),"=v"(d[14]),"=v"(d[15])                          \
    : "v"(base) : "memory")

// coherence-point 8B publish: returning swap (ack == completed at fabric)
__device__ __forceinline__ void swap_store8(void* p, u32x2 d) {
  u32x2 old;
  asm volatile("global_atomic_swap_x2 %0, %1, %2, off sc0 sc1\n\t"
               "s_waitcnt vmcnt(0)"
               : "=v"(old) : "v"(p), "v"(d) : "memory");
}
__device__ __forceinline__ void bar_arrive(unsigned* bar, int l) {
  if (l == 0) {
    unsigned one = 1u;
    asm volatile("global_atomic_add %0, %1, off sc1" :: "v"(bar), "v"(one) : "memory");
  }
}
__device__ __forceinline__ void bar_wait(const unsigned* bar, unsigned tgt) {
  unsigned cur;
  do {
    asm volatile("global_load_dword %0, %1, off sc0 sc1\n\t"
                 "s_waitcnt vmcnt(0)"
                 : "=v"(cur) : "v"(bar) : "memory");
  } while (cur < tgt);
}

// ---------------- prep: Wcat (frag-order bf16), fused biases, lengths ----------------
__global__ void prep_kernel(const int* __restrict__ X,
                            const float* __restrict__ Wr_w, const float* __restrict__ Wz_w,
                            const float* __restrict__ Wxh_w,
                            const float* __restrict__ Wr_b, const float* __restrict__ Ur_b,
                            const float* __restrict__ Wz_b, const float* __restrict__ Uz_b,
                            const float* __restrict__ Wxh_b, const float* __restrict__ Whh_b,
                            u16* __restrict__ Wcat, float* __restrict__ bias_cat,
                            int* __restrict__ lengths) {
  const int bid = blockIdx.x, tid = threadIdx.x;
  if (bid < 64) {
    __shared__ int sred[256];
    int s = 0;
    for (int i = tid; i < 2048; i += 256) s += (X[bid*2048 + i] != 0) ? 1 : 0;
    sred[tid] = s; __syncthreads();
    for (int st = 128; st > 0; st >>= 1) { if (tid < st) sred[tid] += sred[tid + st]; __syncthreads(); }
    if (tid == 0) lengths[bid] = sred[0];
  } else if (bid < 1600) {
    // j = s*16 + (lane&15), k = ks*32 + (lane>>4)*8 + e  (B-fragment order)
    const int eid = (bid - 64)*256 + tid;      // < 393216
    const int e = eid & 7, lane = (eid >> 3) & 63, ks = (eid >> 9) & 7, s = eid >> 12;
    const int j = s*16 + (lane & 15);
    const int k = ks*32 + ((lane >> 4) << 3) + e;
    float v;
    if (j < 512)       v = Wr_w[j*256 + k];
    else if (j < 1024) v = Wz_w[(j-512)*256 + k];
    else               v = Wxh_w[(j-1024)*256 + k];
    Wcat[eid] = (u16)f2bf(v);
  } else {
    const int j = (bid - 1600)*256 + tid;
    if (j < 1536) {
      float v;
      if (j < 512)       v = Wr_b[j] + Ur_b[j];
      else if (j < 1024) v = Wz_b[j-512] + Uz_b[j-512];
      else               v = Wxh_b[j-1024] + Whh_b[j-1024];
      bias_cat[j] = v;
    }
  }
}

// ---------------- gemm_x: xbuf[row][j] = bf16( emb[X] . Wcat_j + bias[j] ) ----------------
__launch_bounds__(256, 2)
__global__ void gemm_x_kernel(const int* __restrict__ X, const float* __restrict__ emb,
                              const u16* __restrict__ Wcat, const float* __restrict__ bias,
                              u16* __restrict__ xbuf, int t0) {
  __shared__ __align__(16) u16 Alds[32768];  // 64 KiB, fragment-ordered A tile
  const int tile = blockIdx.x >> 1, jh = blockIdx.x & 1;
  const int tid = threadIdx.x;
  const int rbase = tile * 128;
#pragma unroll
  for (int c = 0; c < 16; ++c) {
    const int id = c * 256 + tid;
    const int row = id >> 5, k8 = id & 31;
    const int lr = rbase + row;
    const int b = lr & 63, t = t0 + (lr >> 6);
    int v = X[b*2048 + t];
    v = ((unsigned)v < 32000u) ? v : 0;
    s16x8 val = cvt8(emb + (long)v*256 + (k8 << 3));
    const int lane = (row & 15) | ((k8 & 3) << 4);
    const int slot = ((row >> 4)*8 + (k8 >> 2))*64 + lane;
    *(s16x8*)(&Alds[slot << 3]) = val;
  }
  __syncthreads();
  const int w = tid >> 6, l = tid & 63;
  s16x8 af[2][8];
#pragma unroll
  for (int m = 0; m < 2; ++m)
#pragma unroll
    for (int ks = 0; ks < 8; ++ks)
      af[m][ks] = *(const s16x8*)(&Alds[((((w*2+m)*8 + ks)*64) + l) << 3]);
  for (int s = jh*48; s < jh*48 + 48; ++s) {
    s16x8 bfr[8];
    const long wco = (long)s * 4096;
#pragma unroll
    for (int ks = 0; ks < 8; ++ks)
      bfr[ks] = *(const s16x8*)(Wcat + wco + ((ks*64 + l) << 3));
    f32x4 a0 = {0.f,0.f,0.f,0.f}, a1 = {0.f,0.f,0.f,0.f};
#pragma unroll
    for (int ks = 0; ks < 8; ++ks) {
      a0 = MFMA16(af[0][ks], bfr[ks], a0);
      a1 = MFMA16(af[1][ks], bfr[ks], a1);
    }
    const int j = s*16 + (l & 15);
    const float badd = bias[j];
    const int i0 = rbase + w*32 + ((l >> 4) << 2);
#pragma unroll
    for (int e = 0; e < 4; ++e) {
      xbuf[(long)(i0 + e)*1536 + j]      = (u16)f2bf(a0[e] + badd);
      xbuf[(long)(i0 + 16 + e)*1536 + j] = (u16)f2bf(a1[e] + badd);
    }
  }
}

// ---------------- scan: persistent recurrence over one T-chunk ----------------
// 256 single-wave WGs. cluster c = blockIdx&7 owns batch rows [8c,8c+8);
// member m = blockIdx>>3 owns H-dims [16m,16m+16). Weights in LDS (frag order).
__launch_bounds__(64, 1)
__global__ void scan_kernel(const float* __restrict__ Ur_w, const float* __restrict__ Uz_w,
                            const float* __restrict__ Whh_w, const u16* __restrict__ xbuf,
                            const int* __restrict__ lengths, const float* __restrict__ V_w,
                            const float* __restrict__ V_b, u16* __restrict__ h_bc,
                            u16* __restrict__ rh_bc, float* __restrict__ h_final,
                            unsigned* __restrict__ cnt, float* __restrict__ out,
                            int t0, int nsteps, int last) {
  __shared__ __align__(16) u16 Wlds[24576];  // 48 KiB: [mat(3)][ks(16)][lane(64)][e(8)]
  const int wg = blockIdx.x;
  const int c = wg & 7, mem = wg >> 3;
  const int l = threadIdx.x;
  const int n = l & 15, kg = l >> 4;
  const int jb = mem * 16;
  const bool act = (n < 8);
  const int nc = act ? n : 7;
  const int rowb = c * 8;

  // stage recurrent weights to LDS in A-fragment order (single wave, no barrier)
  {
    const float* Ws0 = Ur_w  + (jb + n)*512 + (kg << 3);
    const float* Ws1 = Uz_w  + (jb + n)*512 + (kg << 3);
    const float* Ws2 = Whh_w + (jb + n)*512 + (kg << 3);
#pragma unroll
    for (int ks = 0; ks < 16; ++ks) {
      *(s16x8*)(&Wlds[((     ks)*64 + l) << 3]) = cvt8(Ws0 + ks*32);
      *(s16x8*)(&Wlds[((16 + ks)*64 + l) << 3]) = cvt8(Ws1 + ks*32);
      *(s16x8*)(&Wlds[((32 + ks)*64 + l) << 3]) = cvt8(Ws2 + ks*32);
    }
  }
  const int mylen = lengths[rowb + nc];
  const u16* xp = xbuf + (rowb + nc)*1536 + jb + (kg << 2);
  u16x4 pxr = *(const u16x4*)(xp);
  u16x4 pxz = *(const u16x4*)(xp + 512);
  u16x4 pxh = *(const u16x4*)(xp + 1024);

  const u16* hbp = h_bc  + c*8192 + n*512 + (kg << 3);
  const u16* rbp = rh_bc + c*8192 + n*512 + (kg << 3);
  u16* hst_p = h_bc  + (c*16 + n)*512 + jb + (kg << 2);
  u16* rst_p = rh_bc + (c*16 + n)*512 + jb + (kg << 2);
  unsigned* bar = cnt + c*16;

  float h[4];
  if (t0 == 0) {
    h[0]=0.f; h[1]=0.f; h[2]=0.f; h[3]=0.f;
  } else {
    float4 hv = *(const float4*)(h_final + (rowb + nc)*512 + jb + (kg << 2));
    h[0]=hv.x; h[1]=hv.y; h[2]=hv.z; h[3]=hv.w;
  }
  unsigned gen = 2u * (unsigned)t0;

  for (int tl = 0; tl < nsteps; ++tl) {
    // ---- phase A: [Ur;Uz] @ h ----
    s16x8 hf[16];
    LOAD16_SC64(hf, hbp);                     // coherent h broadcast read
    f32x4 ar = {0.f,0.f,0.f,0.f}, az = {0.f,0.f,0.f,0.f};
#pragma unroll
    for (int ks = 0; ks < 16; ++ks) {
      s16x8 w0 = *(const s16x8*)(&Wlds[((     ks)*64 + l) << 3]);
      s16x8 w1 = *(const s16x8*)(&Wlds[((16 + ks)*64 + l) << 3]);
      ar = MFMA16(w0, hf[ks], ar);
      az = MFMA16(w1, hf[ks], az);
    }
    float zz[4]; unsigned short rb_[4];
#pragma unroll
    for (int e = 0; e < 4; ++e) {
      float rr = sigm(ar[e] + bf2f(pxr[e]));
      zz[e]    = sigm(az[e] + bf2f(pxz[e]));
      rb_[e]   = (unsigned short)f2bf(rr * h[e]);
    }
    if (act) {
      u32x2 d; d[0] = (unsigned)rb_[0] | ((unsigned)rb_[1] << 16);
      d[1] = (unsigned)rb_[2] | ((unsigned)rb_[3] << 16);
      swap_store8(rst_p, d);                  // publish r*h at coherence point
    }
    bar_arrive(bar, l);
    ++gen;
    // prefetch next step's x while polling
    const int tn = (tl < nsteps-1) ? (tl + 1) : tl;
    const u16* xq = xp + tn*98304;
    u16x4 nxr = *(const u16x4*)(xq);
    u16x4 nxz = *(const u16x4*)(xq + 512);
    u16x4 nxh = *(const u16x4*)(xq + 1024);
    bar_wait(bar, 32u*gen);
    // ---- phase B: Whh @ (r*h), gate update ----
    s16x8 rf[16];
    LOAD16_SC64(rf, rbp);
    f32x4 au = {0.f,0.f,0.f,0.f};
#pragma unroll
    for (int ks = 0; ks < 16; ++ks) {
      s16x8 w2 = *(const s16x8*)(&Wlds[((32 + ks)*64 + l) << 3]);
      au = MFMA16(w2, rf[ks], au);
    }
    unsigned short hb_[4];
#pragma unroll
    for (int e = 0; e < 4; ++e) {
      float upd = ftanh(au[e] + bf2f(pxh[e]));
      float hn  = zz[e]*h[e] + (1.f - zz[e])*upd;
      h[e] = ((t0 + tl) < mylen) ? hn : h[e];
      hb_[e] = (unsigned short)f2bf(h[e]);
    }
    if (act) {
      u32x2 d; d[0] = (unsigned)hb_[0] | ((unsigned)hb_[1] << 16);
      d[1] = (unsigned)hb_[2] | ((unsigned)hb_[3] << 16);
      swap_store8(hst_p, d);                  // publish new h
    }
    bar_arrive(bar, l);
    ++gen;
    bar_wait(bar, 32u*gen);
    pxr = nxr; pxz = nxz; pxh = nxh;
  }

  if (!last) {
    // cross-launch handoff: kernel end is a device release, plain store is fine
    if (act) {
      float4 hv; hv.x = h[0]; hv.y = h[1]; hv.z = h[2]; hv.w = h[3];
      *(float4*)(h_final + (rowb + n)*512 + jb + (kg << 2)) = hv;
    }
    return;
  }
  // last launch: publish fp32 h at coherence point, barrier, then output head
  if (act) {
    union { float f; unsigned u; } a0, a1, a2, a3;
    a0.f = h[0]; a1.f = h[1]; a2.f = h[2]; a3.f = h[3];
    float* hp = h_final + (rowb + n)*512 + jb + (kg << 2);
    u32x2 d0; d0[0] = a0.u; d0[1] = a1.u;
    u32x2 d1; d1[0] = a2.u; d1[1] = a3.u;
    swap_store8(hp, d0);
    swap_store8(hp + 2, d1);
  }
  bar_arrive(bar, l);
  ++gen;
  bar_wait(bar, 32u*gen);
  // stage this cluster's 8 rows of h (16 KiB) into LDS via coherent loads
  {
    f32x4 st[16];
    const float* hstage = h_final + rowb*512 + l*64;   // 256 B per lane
    LOAD16_SC16(st, hstage);
    float* hlds = (float*)Wlds;                        // reuse weight LDS
#pragma unroll
    for (int k = 0; k < 16; ++k) *(f32x4*)(&hlds[l*64 + k*4]) = st[k];
  }
  // out = tanh(hT @ V^T + V_b): WG covers its 16 dims x its 8 rows
  {
    const float* hlds = (const float*)Wlds;
    const int nn = l & 7, jo = l >> 3;
    const int j1 = jb + jo, j2 = jb + 8 + jo;
    const float* hrow = hlds + nn*512;
    const float* v1 = V_w + j1*512;
    const float* v2 = V_w + j2*512;
    float a1 = 0.f, a2 = 0.f;
    for (int k = 0; k < 512; k += 4) {
      float4 hv = *(const float4*)(hrow + k);
      float4 w1 = *(const float4*)(v1 + k);
      float4 w2 = *(const float4*)(v2 + k);
      a1 += hv.x*w1.x + hv.y*w1.y + hv.z*w1.z + hv.w*w1.w;
      a2 += hv.x*w2.x + hv.y*w2.y + hv.z*w2.z + hv.w*w2.w;
    }
    out[(rowb + nn)*512 + j1] = ftanh(a1 + V_b[j1]);
    out[(rowb + nn)*512 + j2] = ftanh(a2 + V_b[j2]);
  }
}

extern "C" void kernel_launch(void* const* d_in, const int* in_sizes, int n_in,
                              void* d_out, int out_size, void* d_ws, size_t ws_size,
                              hipStream_t stream) {
  const int*   X     = (const int*)d_in[0];
  const float* emb   = (const float*)d_in[1];
  const float* Wr_w  = (const float*)d_in[2];
  const float* Wr_b  = (const float*)d_in[3];
  const float* Ur_w  = (const float*)d_in[4];
  const float* Ur_b  = (const float*)d_in[5];
  const float* Wz_w  = (const float*)d_in[6];
  const float* Wz_b  = (const float*)d_in[7];
  const float* Uz_w  = (const float*)d_in[8];
  const float* Uz_b  = (const float*)d_in[9];
  const float* Wxh_w = (const float*)d_in[10];
  const float* Wxh_b = (const float*)d_in[11];
  const float* Whh_w = (const float*)d_in[12];
  const float* Whh_b = (const float*)d_in[13];
  const float* V_w   = (const float*)d_in[14];
  const float* V_b   = (const float*)d_in[15];
  (void)in_sizes; (void)n_in; (void)out_size;

  char* ws = (char*)d_ws;
  u16*      Wcat = (u16*)ws;                      //     786,432 B
  float*    bias = (float*)(ws + 786432L);        //       6,144 B
  int*      len  = (int*)(ws + 792576L);          //         256 B
  float*    hfin = (float*)(ws + 792832L);        //     131,072 B
  u16*      hbc  = (u16*)(ws + 923904L);          //     131,072 B
  u16*      rbc  = (u16*)(ws + 1054976L);         //     131,072 B
  unsigned* cnt  = (unsigned*)(ws + 1186048L);    //         512 B
  u16*      xbuf = (u16*)(ws + 1186560L);         // 402,653,184/NC B

  const long avail = (long)ws_size - 1186560L;
  int NC = 1;
  while (NC < 32 && (402653184L / NC) > avail) NC <<= 1;
  const int chunkT = 2048 / NC;

  hipMemsetAsync(hbc, 0, 131072 + 131072 + 512, stream);
  prep_kernel<<<1606, 256, 0, stream>>>(X, Wr_w, Wz_w, Wxh_w, Wr_b, Ur_b, Wz_b, Uz_b,
                                        Wxh_b, Whh_b, Wcat, bias, len);
  for (int c = 0; c < NC; ++c) {
    gemm_x_kernel<<<chunkT, 256, 0, stream>>>(X, emb, Wcat, bias, xbuf, c*chunkT);
    scan_kernel<<<256, 64, 0, stream>>>(Ur_w, Uz_w, Whh_w, xbuf, len, V_w, V_b,
                                        hbc, rbc, hfin, cnt, (float*)d_out,
                                        c*chunkT, chunkT, (c == NC-1) ? 1 : 0);
  }
}